// Round 1
// 649.387 us; speedup vs baseline: 1.0539x; 1.0539x over previous
//
#include <hip/hip_runtime.h>
#include <cstdint>
#include <cstddef>

#define SEQ 1024
#define DM 1024
#define DF 4096
#define NH 16
#define DH 64
#define BSZ 4
#define NTOK (BSZ*SEQ)
#define QKVSZ ((long)NTOK*DM)   // elems per Q/K/V plane

typedef short s16x8 __attribute__((ext_vector_type(8)));
typedef float f32x4 __attribute__((ext_vector_type(4)));

__device__ __forceinline__ unsigned short f2bf(float f) {
  union { float f; unsigned u; } c; c.f = f;
  unsigned u = c.u;
  return (unsigned short)((u + 0x7fffu + ((u >> 16) & 1u)) >> 16);
}
__device__ __forceinline__ float bf2f(unsigned short b) {
  union { unsigned u; float f; } c; c.u = ((unsigned)b) << 16; return c.f;
}

__device__ __forceinline__ void gll16(const void* g, void* l) {
  __builtin_amdgcn_global_load_lds(
      (__attribute__((address_space(1))) void*)(g),
      (__attribute__((address_space(3))) void*)(l), 16, 0, 0);
}

// ---------------------------------------------------------------------------
// Generic bf16 MFMA GEMM: C[m,n] = sum_k A[m,k] * W[n,k]  (+ epilogue)
// EPI: 1 = bf16 store relu(val+bias)
//      3 = f32 store val+bias+resid
//      5 = fused QKV: gn in [0,1024) -> Q*scale bf16; [1024,2048) -> K bf16;
//          [2048,3072) -> V transposed per batch (vt[b][col][s]), ushort4-packed
//      7 = f32 partial store (split-K plane selected by blockIdx.y)
// ---------------------------------------------------------------------------
template<int BM, int BN, int WM, int WN, int EPI>
__launch_bounds__(256)
__global__ void gemm_k(const unsigned short* __restrict__ A,
                       const unsigned short* __restrict__ W,
                       const float* __restrict__ bias,
                       void* __restrict__ outp,
                       const float* __restrict__ resid,
                       int nB, int K, int aRow, int wRow, int oRow,
                       float scale) {
  constexpr int BK = 32;
  __shared__ unsigned short At[BM*BK];
  __shared__ unsigned short Wt[BN*BK];
  const int tid = threadIdx.x;
  const int kz = blockIdx.y;          // split-K plane (0 unless EPI==7 launch)
  A += (long)kz * K;                  // K is the per-plane depth
  W += (long)kz * K;
  float* outF = (float*)outp;
  if (EPI == 7) outF += (long)kz * ((long)(gridDim.x / nB) * BM) * oRow;
  const int mb = (int)blockIdx.x / nB, nb = (int)blockIdx.x % nB;
  const long aBase = (long)mb*BM*aRow;
  const long wBase = (long)nb*BN*wRow;
  const int wave = tid >> 6, lane = tid & 63;
  const int quad = lane >> 4, l16 = lane & 15;
  constexpr int WGN = BN / WN;
  const int wm = (wave / WGN) * WM, wn = (wave % WGN) * WN;
  constexpr int MT = WM/16, NT = WN/16;
  f32x4 acc[MT][NT] = {};
  const int srow = tid >> 2, skof = (tid & 3) * 8;

  for (int k0 = 0; k0 < K; k0 += BK) {
#pragma unroll
    for (int r = 0; r < BM; r += 64)
      gll16(A + aBase + (long)(r + srow)*aRow + k0 + skof, &At[(r + srow)*BK + skof]);
#pragma unroll
    for (int r = 0; r < BN; r += 64)
      gll16(W + wBase + (long)(r + srow)*wRow + k0 + skof, &Wt[(r + srow)*BK + skof]);
    __syncthreads();
    s16x8 af[MT];
#pragma unroll
    for (int mt = 0; mt < MT; ++mt)
      af[mt] = *(const s16x8*)&At[(wm + mt*16 + l16)*BK + quad*8];
#pragma unroll
    for (int nt = 0; nt < NT; ++nt) {
      s16x8 bfr = *(const s16x8*)&Wt[(wn + nt*16 + l16)*BK + quad*8];
#pragma unroll
      for (int mt = 0; mt < MT; ++mt)
        acc[mt][nt] = __builtin_amdgcn_mfma_f32_16x16x32_bf16(af[mt], bfr, acc[mt][nt], 0, 0, 0);
    }
    __syncthreads();
  }

#pragma unroll
  for (int mt = 0; mt < MT; ++mt) {
#pragma unroll
    for (int nt = 0; nt < NT; ++nt) {
      const int gn = nb*BN + wn + nt*16 + l16;
      const float bv = bias ? bias[gn] : 0.f;
      if (EPI == 5) {
        unsigned short* base = (unsigned short*)outp;
        const int reg = gn >> 10, cn = gn & 1023;
        if (reg == 2) {
          // V region: transpose-store; r=0..3 are consecutive s -> pack 8B
          const int gm0 = mb*BM + wm + mt*16 + quad*4;
          const int bb = gm0 >> 10, s0 = gm0 & 1023;
          ushort4 o4;
          o4.x = f2bf(acc[mt][nt][0] + bv);
          o4.y = f2bf(acc[mt][nt][1] + bv);
          o4.z = f2bf(acc[mt][nt][2] + bv);
          o4.w = f2bf(acc[mt][nt][3] + bv);
          *(ushort4*)&base[2*QKVSZ + (long)bb*DM*SEQ + (long)cn*SEQ + s0] = o4;
        } else {
#pragma unroll
          for (int r = 0; r < 4; ++r) {
            const int gm = mb*BM + wm + mt*16 + quad*4 + r;
            const float v = acc[mt][nt][r] + bv;
            if (reg == 0) base[(long)gm*DM + cn] = f2bf(v * scale);
            else          base[QKVSZ + (long)gm*DM + cn] = f2bf(v);
          }
        }
      } else {
#pragma unroll
        for (int r = 0; r < 4; ++r) {
          const int gm = mb*BM + wm + mt*16 + quad*4 + r;
          float v = acc[mt][nt][r] + bv;
          if (EPI == 1) {
            ((unsigned short*)outp)[(long)gm*oRow + gn] = f2bf(v > 0.f ? v : 0.f);
          } else if (EPI == 3) {
            const long o = (long)gm*oRow + gn;
            ((float*)outp)[o] = v + resid[o];
          } else if (EPI == 7) {
            outF[(long)gm*oRow + gn] = v;
          }
        }
      }
    }
  }
}

// ---------------------------------------------------------------------------
// Split-K combine: out = p0 + p1 + bias + resid  (float4 over NTOK*DM)
// ---------------------------------------------------------------------------
__launch_bounds__(256)
__global__ void comb_k(const float* __restrict__ p,
                       const float* __restrict__ b2,
                       const float* __restrict__ out1,
                       float* __restrict__ out) {
  const int i = blockIdx.x * 256 + threadIdx.x;       // float4 index
  const float4 a = ((const float4*)p)[i];
  const float4 b = ((const float4*)(p + (long)NTOK*DM))[i];
  const float4 bb = ((const float4*)b2)[i & (DM/4 - 1)];
  const float4 r = ((const float4*)out1)[i];
  float4 o;
  o.x = a.x + b.x + bb.x + r.x;
  o.y = a.y + b.y + bb.y + r.y;
  o.z = a.z + b.z + bb.z + r.z;
  o.w = a.w + b.w + bb.w + r.w;
  ((float4*)out)[i] = o;
}

// ---------------------------------------------------------------------------
// LayerNorm (torch-style: unbiased var ddof=1, divide by (std + eps)), f32 in,
// bf16 out. One block per token row of 1024.
// ---------------------------------------------------------------------------
__launch_bounds__(256)
__global__ void ln_k(const float* __restrict__ x, const float* __restrict__ g,
                     const float* __restrict__ bta, unsigned short* __restrict__ out) {
  const int row = blockIdx.x, t = threadIdx.x;
  const float4 v = ((const float4*)(x + (long)row*DM))[t];
  __shared__ float red[4];
  float s = v.x + v.y + v.z + v.w;
#pragma unroll
  for (int o = 32; o; o >>= 1) s += __shfl_down(s, o);
  if ((t & 63) == 0) red[t >> 6] = s;
  __syncthreads();
  const float mean = (red[0] + red[1] + red[2] + red[3]) * (1.f/1024.f);
  __syncthreads();
  const float dx = v.x - mean, dy = v.y - mean, dz = v.z - mean, dw = v.w - mean;
  float sq = dx*dx + dy*dy + dz*dz + dw*dw;
#pragma unroll
  for (int o = 32; o; o >>= 1) sq += __shfl_down(sq, o);
  if ((t & 63) == 0) red[t >> 6] = sq;
  __syncthreads();
  const float var = (red[0] + red[1] + red[2] + red[3]) * (1.f/1023.f);
  const float inv = 1.f / (sqrtf(var) + 1e-12f);
  const float4 gv = ((const float4*)g)[t];
  const float4 bv = ((const float4*)bta)[t];
  ushort4 o4;
  o4.x = f2bf(gv.x * dx * inv + bv.x);
  o4.y = f2bf(gv.y * dy * inv + bv.y);
  o4.z = f2bf(gv.z * dz * inv + bv.z);
  o4.w = f2bf(gv.w * dw * inv + bv.w);
  ((ushort4*)(out + (long)row*DM))[t] = o4;
}

// ---------------------------------------------------------------------------
// One-shot conversion of all weights (fp32 -> bf16, QKV concatenated) + bias
// concat. float4-indexed regions; last block copies biases.
// ---------------------------------------------------------------------------
#define R_WQ  262144L
#define R_WK  524288L
#define R_WV  786432L
#define R_W1  1835008L
#define R_W2  2883584L
#define CVT_BLOCKS 11265
__launch_bounds__(256)
__global__ void cvt5_k(const float* __restrict__ wq, const float* __restrict__ wk,
                       const float* __restrict__ wv, const float* __restrict__ w1,
                       const float* __restrict__ w2,
                       const float* __restrict__ bq, const float* __restrict__ bk,
                       const float* __restrict__ bvv,
                       unsigned short* __restrict__ wqkvb,
                       unsigned short* __restrict__ w1b,
                       unsigned short* __restrict__ w2b,
                       float* __restrict__ bcat) {
  const long blk = blockIdx.x;
  if (blk == CVT_BLOCKS - 1) {
    for (int j = threadIdx.x; j < 3072; j += 256)
      bcat[j] = j < 1024 ? bq[j] : (j < 2048 ? bk[j - 1024] : bvv[j - 2048]);
    return;
  }
  long i = blk*256 + threadIdx.x;
  const float* s; unsigned short* d;
  if (i < R_WQ)       { s = wq; d = wqkvb;              }
  else if (i < R_WK)  { s = wk; d = wqkvb + 1048576; i -= R_WQ; }
  else if (i < R_WV)  { s = wv; d = wqkvb + 2097152; i -= R_WK; }
  else if (i < R_W1)  { s = w1; d = w1b;             i -= R_WV; }
  else                { s = w2; d = w2b;             i -= R_W1; }
  const float4 v = ((const float4*)s)[i];
  ushort4 o; o.x = f2bf(v.x); o.y = f2bf(v.y); o.z = f2bf(v.z); o.w = f2bf(v.w);
  ((ushort4*)d)[i] = o;
}

// ---------------------------------------------------------------------------
// Fused scores + softmax + attn write + P@V + residual.
// Block = 16 q rows x one (b,h). Wave w owns score cols [w*256, w*256+256).
// attn output written DIRECTLY from registers in f32 (exact normalize, no
// bf16 round trip). P (bf16) staged to LDS only for the PV MFMA A-operand.
// ---------------------------------------------------------------------------
#define LDP 1032   // P row stride in bf16 (1024 + 8 pad): 2-way-max banks
__launch_bounds__(256)
__global__ void attn_k(const unsigned short* __restrict__ Q,
                       const unsigned short* __restrict__ Kb,
                       const unsigned short* __restrict__ vt,
                       const float* __restrict__ xres,
                       float* __restrict__ attn_f,
                       float* __restrict__ out1) {
  const int b = blockIdx.y, h = blockIdx.z;
  const int q0 = blockIdx.x * 16;
  const int wave = threadIdx.x >> 6, lane = threadIdx.x & 63;
  const int quad = lane >> 4, l16 = lane & 15;
  __shared__ unsigned short PL[16 * LDP];
  __shared__ float red[4][16];

  // ---- scores: S[q0+.., :] = (Q*0.125) @ K^T  (Q pre-scaled) ----
  const unsigned short* Qb = Q + (long)b*SEQ*DM + h*DH;
  const unsigned short* Kh = Kb + (long)b*SEQ*DM + h*DH;
  s16x8 af[2];
#pragma unroll
  for (int ks = 0; ks < 2; ++ks)
    af[ks] = *(const s16x8*)&Qb[(long)(q0 + l16)*DM + ks*32 + quad*8];
  f32x4 acc[16];
#pragma unroll
  for (int nt = 0; nt < 16; ++nt) acc[nt] = (f32x4){0.f, 0.f, 0.f, 0.f};
  for (int nt = 0; nt < 16; ++nt) {
    const int kc = wave*256 + nt*16 + l16;
#pragma unroll
    for (int ks = 0; ks < 2; ++ks) {
      const s16x8 bfr = *(const s16x8*)&Kh[(long)kc*DM + ks*32 + quad*8];
      acc[nt] = __builtin_amdgcn_mfma_f32_16x16x32_bf16(af[ks], bfr, acc[nt], 0, 0, 0);
    }
  }

  // ---- softmax ----
  float rmax[4];
#pragma unroll
  for (int r = 0; r < 4; ++r) {
    float m = -3e38f;
#pragma unroll
    for (int nt = 0; nt < 16; ++nt) m = fmaxf(m, acc[nt][r]);
#pragma unroll
    for (int o = 1; o < 16; o <<= 1) m = fmaxf(m, __shfl_xor(m, o));
    rmax[r] = m;
  }
  if (l16 == 0) {
#pragma unroll
    for (int r = 0; r < 4; ++r) red[wave][quad*4 + r] = rmax[r];
  }
  __syncthreads();
#pragma unroll
  for (int r = 0; r < 4; ++r)
    rmax[r] = fmaxf(fmaxf(red[0][quad*4+r], red[1][quad*4+r]),
                    fmaxf(red[2][quad*4+r], red[3][quad*4+r]));
  __syncthreads();
#pragma unroll
  for (int r = 0; r < 4; ++r) {
    float s = 0.f;
#pragma unroll
    for (int nt = 0; nt < 16; ++nt) {
      const float e = __expf(acc[nt][r] - rmax[r]);
      acc[nt][r] = e; s += e;
    }
#pragma unroll
    for (int o = 1; o < 16; o <<= 1) s += __shfl_xor(s, o);
    if (l16 == 0) red[wave][quad*4 + r] = s;
  }
  __syncthreads();

  // ---- normalize; stage P (bf16) to LDS; write attn_f (f32) from regs ----
  const long obase = (long)(h*BSZ + b)*SEQ*SEQ + (long)q0*SEQ;
#pragma unroll
  for (int r = 0; r < 4; ++r) {
    const float tot = red[0][quad*4+r] + red[1][quad*4+r] + red[2][quad*4+r] + red[3][quad*4+r];
    const float inv = 1.f / tot;
    unsigned short* prow = &PL[(quad*4 + r)*LDP + wave*256 + l16];
    float* arow = attn_f + obase + (long)(quad*4 + r)*SEQ + wave*256 + l16;
#pragma unroll
    for (int nt = 0; nt < 16; ++nt) {
      const float pv_ = acc[nt][r] * inv;
      prow[nt*16] = f2bf(pv_);
      arow[nt*16] = pv_;
    }
  }
  __syncthreads();

  // ---- ctx = P @ V_h : wave owns output cols [wave*16, wave*16+16) ----
  // 4 independent accumulator chains (8-deep) instead of one 32-deep chain.
  f32x4 cc[4] = {};
  const unsigned short* Vh = vt + (long)b*DM*SEQ + (long)(h*DH + wave*16 + l16)*SEQ;
#pragma unroll
  for (int k0 = 0; k0 < 32; ++k0) {
    const s16x8 a  = *(const s16x8*)&PL[l16*LDP + k0*32 + quad*8];
    const s16x8 bf = *(const s16x8*)&Vh[k0*32 + quad*8];
    cc[k0 & 3] = __builtin_amdgcn_mfma_f32_16x16x32_bf16(a, bf, cc[k0 & 3], 0, 0, 0);
  }
  const f32x4 c = (cc[0] + cc[1]) + (cc[2] + cc[3]);

  // ---- out1 = ctx + x ----
#pragma unroll
  for (int r = 0; r < 4; ++r) {
    const int gq = q0 + quad*4 + r;
    const int col = h*DH + wave*16 + l16;
    const long idx = (long)b*SEQ*DM + (long)gq*DM + col;
    out1[idx] = c[r] + xres[idx];
  }
}

extern "C" void kernel_launch(void* const* d_in, const int* in_sizes, int n_in,
                              void* d_out, int out_size, void* d_ws, size_t ws_size,
                              hipStream_t stream) {
  const float* x    = (const float*)d_in[0];
  const float* ln1g = (const float*)d_in[1];
  const float* ln1b = (const float*)d_in[2];
  const float* wq   = (const float*)d_in[3];
  const float* bq   = (const float*)d_in[4];
  const float* wk   = (const float*)d_in[5];
  const float* bk   = (const float*)d_in[6];
  const float* wv   = (const float*)d_in[7];
  const float* bv   = (const float*)d_in[8];
  const float* ln2g = (const float*)d_in[9];
  const float* ln2b = (const float*)d_in[10];
  const float* w1   = (const float*)d_in[11];
  const float* b1   = (const float*)d_in[12];
  const float* w2   = (const float*)d_in[13];
  const float* b2   = (const float*)d_in[14];
  float* out    = (float*)d_out;
  float* attn_f = out + (long)NTOK*DM;

  uint8_t* p = (uint8_t*)d_ws;
  auto alloc = [&](size_t bytes) {
    uint8_t* r = p; p += (bytes + 255) & ~(size_t)255; return r;
  };
  unsigned short* hbuf  = (unsigned short*)alloc((size_t)NTOK*DM*2);   // LN1(x)
  unsigned short* qkv   = (unsigned short*)alloc((size_t)3*NTOK*DM*2); // Q|K|V^T
  unsigned short* h2    = (unsigned short*)alloc((size_t)NTOK*DM*2);   // LN2(out1)
  unsigned short* f1    = (unsigned short*)alloc((size_t)NTOK*DF*2);   // relu(ff1)
  float*          out1  = (float*)alloc((size_t)NTOK*DM*4);            // ctx + x
  unsigned short* wqkvb = (unsigned short*)alloc((size_t)3*DM*DM*2);
  unsigned short* w1b   = (unsigned short*)alloc((size_t)DF*DM*2);
  unsigned short* w2b   = (unsigned short*)alloc((size_t)DM*DF*2);
  float*          bcat  = (float*)alloc((size_t)3*DM*4);
  float*          part  = (float*)alloc((size_t)2*NTOK*DM*4);          // split-K partials

  // 1. all weights -> bf16 (QKV concatenated) + bias concat
  cvt5_k<<<CVT_BLOCKS, 256, 0, stream>>>(wq, wk, wv, w1, w2, bq, bk, bv,
                                         wqkvb, w1b, w2b, bcat);
  // 2. LN1
  ln_k<<<NTOK, 256, 0, stream>>>(x, ln1g, ln1b, hbuf);

  // 3. fused QKV projection (Q pre-scaled 1/8, V stored transposed)
  gemm_k<128,128,64,64,5><<<dim3((NTOK/128)*(3*DM/128)), 256, 0, stream>>>(
      hbuf, wqkvb, bcat, qkv, nullptr, 3*DM/128, DM, DM, DM, DM, 0.125f);

  // 4. fused scores + softmax + attn write + PV + residual
  attn_k<<<dim3(SEQ/16, BSZ, NH), 256, 0, stream>>>(
      qkv, qkv + QKVSZ, qkv + 2*QKVSZ, x, attn_f, out1);

  // 5. LN2
  ln_k<<<NTOK, 256, 0, stream>>>(out1, ln2g, ln2b, h2);

  // 6. ff1 = relu(h2 @ w1^T + b1)
  gemm_k<128,128,64,64,1><<<dim3((NTOK/128)*(DF/128)), 256, 0, stream>>>(
      h2, w1b, b1, f1, nullptr, DF/128, DM, DM, DM, DF, 1.f);

  // 7. out = ff1 @ w2^T + b2 + out1 -> d_out  (split-K=2: 512 blocks, 2/CU)
  gemm_k<128,128,64,64,7><<<dim3((NTOK/128)*(DM/128), 2), 256, 0, stream>>>(
      f1, w2b, nullptr, part, nullptr, DM/128, DF/2, DF, DF, DM, 1.f);
  comb_k<<<(NTOK*DM)/1024, 256, 0, stream>>>(part, b2, out1, out);
}

// Round 3
// 611.594 us; speedup vs baseline: 1.1191x; 1.0618x over previous
//
#include <hip/hip_runtime.h>
#include <cstdint>
#include <cstddef>

#define SEQ 1024
#define DM 1024
#define DF 4096
#define NH 16
#define DH 64
#define BSZ 4
#define NTOK (BSZ*SEQ)
#define QKVSZ ((long)NTOK*DM)   // elems per Q/K/V plane

typedef short s16x8 __attribute__((ext_vector_type(8)));
typedef float f32x4 __attribute__((ext_vector_type(4)));

__device__ __forceinline__ unsigned short f2bf(float f) {
  union { float f; unsigned u; } c; c.f = f;
  unsigned u = c.u;
  return (unsigned short)((u + 0x7fffu + ((u >> 16) & 1u)) >> 16);
}
__device__ __forceinline__ float bf2f(unsigned short b) {
  union { unsigned u; float f; } c; c.u = ((unsigned)b) << 16; return c.f;
}

__device__ __forceinline__ void gll16(const void* g, void* l) {
  __builtin_amdgcn_global_load_lds(
      (__attribute__((address_space(1))) void*)(g),
      (__attribute__((address_space(3))) void*)(l), 16, 0, 0);
}

// ---------------------------------------------------------------------------
// 256x256 8-wave BK=64 pipelined GEMM (T1+T2+T3+T4+T5).
//   C[m,n] = sum_k A[m,k] * W[n,k]  (+ epilogue)
// 8 waves as 2(M)x4(N); per-wave 128x64 out; 4 phases per K-tile, each phase
// = one quadrant (mhalf,nhalf): 12 ds_read_b128 + 2 global_load_lds + raw
// barrier + 16 MFMA wrapped in setprio. Counted vmcnt(2) once per K-tile.
// LDS 128 KiB STATIC (no dynamic-shared attribute machinery):
//   A[2buf][256r][8chunks16B] at 0, B same at +64 KiB.
// XOR swizzle chunk^=(row&7) applied on the GLOBAL source (linear LDS dest,
// rule 21) and on the ds_read address -> even bank spread (conflict-free).
// Staging schedule (quarter q = 64 rows = 1 gll16/thread):
//   p1(t): A1,A3(t+1)->nxt   p2(t): B0,B1(t+1)->nxt
//   p3(t): B2,B3(t+1)->nxt   p4(t): A0,A2(t+2)->cur ; vmcnt(2)
// Hazard-checked: each region overwritten >=2 barriers after its last
// cross-wave read completes; counted wait lands every quarter one tile
// before first use; tail drains vmcnt(0) at t=NTt-2.
// EPI: 1 = bf16 store relu(val+bias)
//      5 = fused QKV (Q*scale | K | V^T ushort4-packed)
//      7 = f32 partial store, plane = blockIdx.y (split-K)
// ---------------------------------------------------------------------------
template<int EPI>
__launch_bounds__(512, 2)
__global__ void gemm8_k(const unsigned short* __restrict__ A,
                        const unsigned short* __restrict__ W,
                        const float* __restrict__ bias,
                        void* __restrict__ outp,
                        int nNB, int K, int aRow, int wRow, int oRow,
                        float scale, long planeStride) {
  __shared__ __align__(16) char smem[131072];
  const int tid = threadIdx.x;
  const int kz = blockIdx.y;
  // T1: XCD-chunked block swizzle (all grids divisible by 8 -> bijective)
  const int cpx = (int)gridDim.x >> 3;
  const int wgid = ((int)blockIdx.x & 7) * cpx + ((int)blockIdx.x >> 3);
  const int mb = wgid / nNB, nb = wgid % nNB;
  const unsigned short* Ag = A + (long)mb*256*aRow + (long)kz*K;
  const unsigned short* Wg = W + (long)nb*256*wRow + (long)kz*K;
  const int wave = tid >> 6, lane = tid & 63;
  const int quad = lane >> 4, l16 = lane & 15;
  const int wr = wave >> 2, wc = wave & 3;
  // staging constants: thread covers 16B unit (srow, sch) of a 64-row quarter
  const int srow = tid >> 3, sch = tid & 7;
  const int swz = sch ^ (srow & 7);        // pre-swizzled global chunk
  const int ldst = tid << 4;               // linear LDS byte slot
  f32x4 acc[8][4] = {};

  auto stageA = [&](int q, int t, int buf) {
    gll16(Ag + (long)(q*64 + srow)*aRow + t*64 + swz*8,
          smem + buf*32768 + q*8192 + ldst);
  };
  auto stageB = [&](int q, int t, int buf) {
    gll16(Wg + (long)(q*64 + srow)*wRow + t*64 + swz*8,
          smem + 65536 + buf*32768 + q*8192 + ldst);
  };

  const int NTt = K >> 6;
  // prologue: full tile 0, then A0,A2(1); leave those 2 in flight
  stageA(0,0,0); stageA(2,0,0); stageA(1,0,0); stageA(3,0,0);
  stageB(0,0,0); stageB(1,0,0); stageB(2,0,0); stageB(3,0,0);
  if (NTt > 1) {
    stageA(0,1,1); stageA(2,1,1);
    asm volatile("s_waitcnt vmcnt(2)" ::: "memory");
  } else {
    asm volatile("s_waitcnt vmcnt(0)" ::: "memory");
  }
  asm volatile("" ::: "memory"); __builtin_amdgcn_s_barrier();
  asm volatile("" ::: "memory");

  for (int t = 0; t < NTt; ++t) {
    const int cur = t & 1, nxt = cur ^ 1;
    const char* Ab = smem + cur*32768;
    const char* Bb = smem + 65536 + cur*32768;

#define G8_PHASE(MHF, NHF, STAGE_STMT, WAIT_STMT)                                \
    {                                                                            \
      s16x8 afr[4][2]; s16x8 bfr[2][2];                                          \
      _Pragma("unroll") for (int mf = 0; mf < 4; ++mf)                           \
      _Pragma("unroll") for (int ks = 0; ks < 2; ++ks) {                         \
        const int ra = wr*128 + MHF*64 + mf*16 + l16;                            \
        afr[mf][ks] = *(const s16x8*)(Ab + ra*128 + (((ks*4+quad)^(ra&7))<<4));  \
      }                                                                          \
      _Pragma("unroll") for (int nf = 0; nf < 2; ++nf)                           \
      _Pragma("unroll") for (int ks = 0; ks < 2; ++ks) {                         \
        const int rb = wc*64 + NHF*32 + nf*16 + l16;                             \
        bfr[nf][ks] = *(const s16x8*)(Bb + rb*128 + (((ks*4+quad)^(rb&7))<<4));  \
      }                                                                          \
      STAGE_STMT;                                                                \
      WAIT_STMT;                                                                 \
      asm volatile("" ::: "memory"); __builtin_amdgcn_s_barrier();               \
      asm volatile("" ::: "memory");                                             \
      __builtin_amdgcn_s_setprio(1);                                             \
      _Pragma("unroll") for (int nf = 0; nf < 2; ++nf)                           \
      _Pragma("unroll") for (int mf = 0; mf < 4; ++mf)                           \
      _Pragma("unroll") for (int ks = 0; ks < 2; ++ks)                           \
        acc[MHF*4+mf][NHF*2+nf] = __builtin_amdgcn_mfma_f32_16x16x32_bf16(       \
            afr[mf][ks], bfr[nf][ks], acc[MHF*4+mf][NHF*2+nf], 0, 0, 0);         \
      __builtin_amdgcn_s_setprio(0);                                             \
      asm volatile("" ::: "memory"); __builtin_amdgcn_s_barrier();               \
      asm volatile("" ::: "memory");                                             \
    }

    G8_PHASE(0, 0,
      if (t+1 < NTt) { stageA(1, t+1, nxt); stageA(3, t+1, nxt); }, )
    G8_PHASE(0, 1,
      if (t+1 < NTt) { stageB(0, t+1, nxt); stageB(1, t+1, nxt); }, )
    G8_PHASE(1, 0,
      if (t+1 < NTt) { stageB(2, t+1, nxt); stageB(3, t+1, nxt); }, )
    G8_PHASE(1, 1,
      if (t+2 < NTt) { stageA(0, t+2, cur); stageA(2, t+2, cur); },
      if (t+2 < NTt) { asm volatile("s_waitcnt vmcnt(2)" ::: "memory"); }
      else if (t+1 < NTt) { asm volatile("s_waitcnt vmcnt(0)" ::: "memory"); })
#undef G8_PHASE
  }

  // ---- epilogue ----
#pragma unroll
  for (int mt = 0; mt < 8; ++mt) {
#pragma unroll
    for (int nt = 0; nt < 4; ++nt) {
      const int gn = nb*256 + wc*64 + nt*16 + l16;
      const float bv = (EPI == 1 || EPI == 5) ? bias[gn] : 0.f;
      if (EPI == 5) {
        unsigned short* base = (unsigned short*)outp;
        const int reg = gn >> 10, cn = gn & 1023;
        if (reg == 2) {
          const int gm0 = mb*256 + wr*128 + mt*16 + quad*4;
          const int bb = gm0 >> 10, s0 = gm0 & 1023;
          ushort4 o4;
          o4.x = f2bf(acc[mt][nt][0] + bv);
          o4.y = f2bf(acc[mt][nt][1] + bv);
          o4.z = f2bf(acc[mt][nt][2] + bv);
          o4.w = f2bf(acc[mt][nt][3] + bv);
          *(ushort4*)&base[2*QKVSZ + (long)bb*DM*SEQ + (long)cn*SEQ + s0] = o4;
        } else {
#pragma unroll
          for (int r = 0; r < 4; ++r) {
            const int gm = mb*256 + wr*128 + mt*16 + quad*4 + r;
            const float v = acc[mt][nt][r] + bv;
            if (reg == 0) base[(long)gm*DM + cn] = f2bf(v * scale);
            else          base[QKVSZ + (long)gm*DM + cn] = f2bf(v);
          }
        }
      } else {
#pragma unroll
        for (int r = 0; r < 4; ++r) {
          const int gm = mb*256 + wr*128 + mt*16 + quad*4 + r;
          const float v = acc[mt][nt][r] + bv;
          if (EPI == 1) {
            ((unsigned short*)outp)[(long)gm*oRow + gn] = f2bf(v > 0.f ? v : 0.f);
          } else if (EPI == 7) {
            ((float*)outp)[(long)kz*planeStride + (long)gm*oRow + gn] = v;
          }
        }
      }
    }
  }
}

// ---------------------------------------------------------------------------
// Split-K combine: out = p0+p1+p2+p3 + bias + resid  (float4 over NTOK*DM)
// ---------------------------------------------------------------------------
__launch_bounds__(256)
__global__ void comb_k(const float* __restrict__ p,
                       const float* __restrict__ b2,
                       const float* __restrict__ out1,
                       float* __restrict__ out) {
  const int i = blockIdx.x * 256 + threadIdx.x;       // float4 index
  const float4 a0 = ((const float4*)p)[i];
  const float4 a1 = ((const float4*)(p + (long)NTOK*DM))[i];
  const float4 a2 = ((const float4*)(p + 2L*NTOK*DM))[i];
  const float4 a3 = ((const float4*)(p + 3L*NTOK*DM))[i];
  const float4 bb = ((const float4*)b2)[i & (DM/4 - 1)];
  const float4 r = ((const float4*)out1)[i];
  float4 o;
  o.x = (a0.x + a1.x) + (a2.x + a3.x) + bb.x + r.x;
  o.y = (a0.y + a1.y) + (a2.y + a3.y) + bb.y + r.y;
  o.z = (a0.z + a1.z) + (a2.z + a3.z) + bb.z + r.z;
  o.w = (a0.w + a1.w) + (a2.w + a3.w) + bb.w + r.w;
  ((float4*)out)[i] = o;
}

// ---------------------------------------------------------------------------
// LayerNorm (torch-style: unbiased var ddof=1, divide by (std + eps)), f32 in,
// bf16 out. One block per token row of 1024.
// ---------------------------------------------------------------------------
__launch_bounds__(256)
__global__ void ln_k(const float* __restrict__ x, const float* __restrict__ g,
                     const float* __restrict__ bta, unsigned short* __restrict__ out) {
  const int row = blockIdx.x, t = threadIdx.x;
  const float4 v = ((const float4*)(x + (long)row*DM))[t];
  __shared__ float red[4];
  float s = v.x + v.y + v.z + v.w;
#pragma unroll
  for (int o = 32; o; o >>= 1) s += __shfl_down(s, o);
  if ((t & 63) == 0) red[t >> 6] = s;
  __syncthreads();
  const float mean = (red[0] + red[1] + red[2] + red[3]) * (1.f/1024.f);
  __syncthreads();
  const float dx = v.x - mean, dy = v.y - mean, dz = v.z - mean, dw = v.w - mean;
  float sq = dx*dx + dy*dy + dz*dz + dw*dw;
#pragma unroll
  for (int o = 32; o; o >>= 1) sq += __shfl_down(sq, o);
  if ((t & 63) == 0) red[t >> 6] = sq;
  __syncthreads();
  const float var = (red[0] + red[1] + red[2] + red[3]) * (1.f/1023.f);
  const float inv = 1.f / (sqrtf(var) + 1e-12f);
  const float4 gv = ((const float4*)g)[t];
  const float4 bv = ((const float4*)bta)[t];
  ushort4 o4;
  o4.x = f2bf(gv.x * dx * inv + bv.x);
  o4.y = f2bf(gv.y * dy * inv + bv.y);
  o4.z = f2bf(gv.z * dz * inv + bv.z);
  o4.w = f2bf(gv.w * dw * inv + bv.w);
  ((ushort4*)(out + (long)row*DM))[t] = o4;
}

// ---------------------------------------------------------------------------
// One-shot conversion of all weights (fp32 -> bf16, QKV concatenated) + bias
// concat. float4-indexed regions; last block copies biases.
// ---------------------------------------------------------------------------
#define R_WQ  262144L
#define R_WK  524288L
#define R_WV  786432L
#define R_W1  1835008L
#define R_W2  2883584L
#define CVT_BLOCKS 11265
__launch_bounds__(256)
__global__ void cvt5_k(const float* __restrict__ wq, const float* __restrict__ wk,
                       const float* __restrict__ wv, const float* __restrict__ w1,
                       const float* __restrict__ w2,
                       const float* __restrict__ bq, const float* __restrict__ bk,
                       const float* __restrict__ bvv,
                       unsigned short* __restrict__ wqkvb,
                       unsigned short* __restrict__ w1b,
                       unsigned short* __restrict__ w2b,
                       float* __restrict__ bcat) {
  const long blk = blockIdx.x;
  if (blk == CVT_BLOCKS - 1) {
    for (int j = threadIdx.x; j < 3072; j += 256)
      bcat[j] = j < 1024 ? bq[j] : (j < 2048 ? bk[j - 1024] : bvv[j - 2048]);
    return;
  }
  long i = blk*256 + threadIdx.x;
  const float* s; unsigned short* d;
  if (i < R_WQ)       { s = wq; d = wqkvb;              }
  else if (i < R_WK)  { s = wk; d = wqkvb + 1048576; i -= R_WQ; }
  else if (i < R_WV)  { s = wv; d = wqkvb + 2097152; i -= R_WK; }
  else if (i < R_W1)  { s = w1; d = w1b;             i -= R_WV; }
  else                { s = w2; d = w2b;             i -= R_W1; }
  const float4 v = ((const float4*)s)[i];
  ushort4 o; o.x = f2bf(v.x); o.y = f2bf(v.y); o.z = f2bf(v.z); o.w = f2bf(v.w);
  ((ushort4*)d)[i] = o;
}

// ---------------------------------------------------------------------------
// Fused scores + softmax + attn write + P@V + residual.
// Block = 16 q rows x one (b,h). Wave w owns score cols [w*256, w*256+256).
// attn output written DIRECTLY from registers in f32 (exact normalize, no
// bf16 round trip). P (bf16) staged to LDS only for the PV MFMA A-operand.
// ---------------------------------------------------------------------------
#define LDP 1032   // P row stride in bf16 (1024 + 8 pad): 2-way-max banks
__launch_bounds__(256)
__global__ void attn_k(const unsigned short* __restrict__ Q,
                       const unsigned short* __restrict__ Kb,
                       const unsigned short* __restrict__ vt,
                       const float* __restrict__ xres,
                       float* __restrict__ attn_f,
                       float* __restrict__ out1) {
  const int b = blockIdx.y, h = blockIdx.z;
  const int q0 = blockIdx.x * 16;
  const int wave = threadIdx.x >> 6, lane = threadIdx.x & 63;
  const int quad = lane >> 4, l16 = lane & 15;
  __shared__ unsigned short PL[16 * LDP];
  __shared__ float red[4][16];

  // ---- scores: S[q0+.., :] = (Q*0.125) @ K^T  (Q pre-scaled) ----
  const unsigned short* Qb = Q + (long)b*SEQ*DM + h*DH;
  const unsigned short* Kh = Kb + (long)b*SEQ*DM + h*DH;
  s16x8 af[2];
#pragma unroll
  for (int ks = 0; ks < 2; ++ks)
    af[ks] = *(const s16x8*)&Qb[(long)(q0 + l16)*DM + ks*32 + quad*8];
  f32x4 acc[16];
#pragma unroll
  for (int nt = 0; nt < 16; ++nt) acc[nt] = (f32x4){0.f, 0.f, 0.f, 0.f};
  for (int nt = 0; nt < 16; ++nt) {
    const int kc = wave*256 + nt*16 + l16;
#pragma unroll
    for (int ks = 0; ks < 2; ++ks) {
      const s16x8 bfr = *(const s16x8*)&Kh[(long)kc*DM + ks*32 + quad*8];
      acc[nt] = __builtin_amdgcn_mfma_f32_16x16x32_bf16(af[ks], bfr, acc[nt], 0, 0, 0);
    }
  }

  // ---- softmax ----
  float rmax[4];
#pragma unroll
  for (int r = 0; r < 4; ++r) {
    float m = -3e38f;
#pragma unroll
    for (int nt = 0; nt < 16; ++nt) m = fmaxf(m, acc[nt][r]);
#pragma unroll
    for (int o = 1; o < 16; o <<= 1) m = fmaxf(m, __shfl_xor(m, o));
    rmax[r] = m;
  }
  if (l16 == 0) {
#pragma unroll
    for (int r = 0; r < 4; ++r) red[wave][quad*4 + r] = rmax[r];
  }
  __syncthreads();
#pragma unroll
  for (int r = 0; r < 4; ++r)
    rmax[r] = fmaxf(fmaxf(red[0][quad*4+r], red[1][quad*4+r]),
                    fmaxf(red[2][quad*4+r], red[3][quad*4+r]));
  __syncthreads();
#pragma unroll
  for (int r = 0; r < 4; ++r) {
    float s = 0.f;
#pragma unroll
    for (int nt = 0; nt < 16; ++nt) {
      const float e = __expf(acc[nt][r] - rmax[r]);
      acc[nt][r] = e; s += e;
    }
#pragma unroll
    for (int o = 1; o < 16; o <<= 1) s += __shfl_xor(s, o);
    if (l16 == 0) red[wave][quad*4 + r] = s;
  }
  __syncthreads();

  // ---- normalize; stage P (bf16) to LDS; write attn_f (f32) from regs ----
  const long obase = (long)(h*BSZ + b)*SEQ*SEQ + (long)q0*SEQ;
#pragma unroll
  for (int r = 0; r < 4; ++r) {
    const float tot = red[0][quad*4+r] + red[1][quad*4+r] + red[2][quad*4+r] + red[3][quad*4+r];
    const float inv = 1.f / tot;
    unsigned short* prow = &PL[(quad*4 + r)*LDP + wave*256 + l16];
    float* arow = attn_f + obase + (long)(quad*4 + r)*SEQ + wave*256 + l16;
#pragma unroll
    for (int nt = 0; nt < 16; ++nt) {
      const float pv_ = acc[nt][r] * inv;
      prow[nt*16] = f2bf(pv_);
      arow[nt*16] = pv_;
    }
  }
  __syncthreads();

  // ---- ctx = P @ V_h : wave owns output cols [wave*16, wave*16+16) ----
  f32x4 cc[4] = {};
  const unsigned short* Vh = vt + (long)b*DM*SEQ + (long)(h*DH + wave*16 + l16)*SEQ;
#pragma unroll
  for (int k0 = 0; k0 < 32; ++k0) {
    const s16x8 a  = *(const s16x8*)&PL[l16*LDP + k0*32 + quad*8];
    const s16x8 bf = *(const s16x8*)&Vh[k0*32 + quad*8];
    cc[k0 & 3] = __builtin_amdgcn_mfma_f32_16x16x32_bf16(a, bf, cc[k0 & 3], 0, 0, 0);
  }
  const f32x4 c = (cc[0] + cc[1]) + (cc[2] + cc[3]);

  // ---- out1 = ctx + x ----
#pragma unroll
  for (int r = 0; r < 4; ++r) {
    const int gq = q0 + quad*4 + r;
    const int col = h*DH + wave*16 + l16;
    const long idx = (long)b*SEQ*DM + (long)gq*DM + col;
    out1[idx] = c[r] + xres[idx];
  }
}

extern "C" void kernel_launch(void* const* d_in, const int* in_sizes, int n_in,
                              void* d_out, int out_size, void* d_ws, size_t ws_size,
                              hipStream_t stream) {
  const float* x    = (const float*)d_in[0];
  const float* ln1g = (const float*)d_in[1];
  const float* ln1b = (const float*)d_in[2];
  const float* wq   = (const float*)d_in[3];
  const float* bq   = (const float*)d_in[4];
  const float* wk   = (const float*)d_in[5];
  const float* bk   = (const float*)d_in[6];
  const float* wv   = (const float*)d_in[7];
  const float* bv   = (const float*)d_in[8];
  const float* ln2g = (const float*)d_in[9];
  const float* ln2b = (const float*)d_in[10];
  const float* w1   = (const float*)d_in[11];
  const float* b1   = (const float*)d_in[12];
  const float* w2   = (const float*)d_in[13];
  const float* b2   = (const float*)d_in[14];
  float* out    = (float*)d_out;
  float* attn_f = out + (long)NTOK*DM;

  uint8_t* p = (uint8_t*)d_ws;
  auto alloc = [&](size_t bytes) {
    uint8_t* r = p; p += (bytes + 255) & ~(size_t)255; return r;
  };
  unsigned short* hbuf  = (unsigned short*)alloc((size_t)NTOK*DM*2);   // LN1(x)
  unsigned short* qkv   = (unsigned short*)alloc((size_t)3*NTOK*DM*2); // Q|K|V^T
  unsigned short* h2    = (unsigned short*)alloc((size_t)NTOK*DM*2);   // LN2(out1)
  unsigned short* f1    = (unsigned short*)alloc((size_t)NTOK*DF*2);   // relu(ff1)
  float*          out1  = (float*)alloc((size_t)NTOK*DM*4);            // ctx + x
  unsigned short* wqkvb = (unsigned short*)alloc((size_t)3*DM*DM*2);
  unsigned short* w1b   = (unsigned short*)alloc((size_t)DF*DM*2);
  unsigned short* w2b   = (unsigned short*)alloc((size_t)DM*DF*2);
  float*          bcat  = (float*)alloc((size_t)3*DM*4);
  float*          part  = (float*)alloc((size_t)4*NTOK*DM*4);          // split-K partials

  // 1. all weights -> bf16 (QKV concatenated) + bias concat
  cvt5_k<<<CVT_BLOCKS, 256, 0, stream>>>(wq, wk, wv, w1, w2, bq, bk, bv,
                                         wqkvb, w1b, w2b, bcat);
  // 2. LN1
  ln_k<<<NTOK, 256, 0, stream>>>(x, ln1g, ln1b, hbuf);

  // 3. fused QKV projection (Q pre-scaled 1/8, V stored transposed) - 256^2
  gemm8_k<5><<<dim3((NTOK/256)*(3*DM/256)), 512, 0, stream>>>(
      hbuf, wqkvb, bcat, qkv, 3*DM/256, DM, DM, DM, DM, 0.125f, 0);

  // 4. fused scores + softmax + attn write + PV + residual
  attn_k<<<dim3(SEQ/16, BSZ, NH), 256, 0, stream>>>(
      qkv, qkv + QKVSZ, qkv + 2*QKVSZ, x, attn_f, out1);

  // 5. LN2
  ln_k<<<NTOK, 256, 0, stream>>>(out1, ln2g, ln2b, h2);

  // 6. ff1 = relu(h2 @ w1^T + b1) - 256^2
  gemm8_k<1><<<dim3((NTOK/256)*(DF/256)), 512, 0, stream>>>(
      h2, w1b, b1, f1, DF/256, DM, DM, DM, DF, 1.f, 0);

  // 7. split-K=4 FF2 partials (256 blocks = 1/CU) + combine
  gemm8_k<7><<<dim3((NTOK/256)*(DM/256), 4), 512, 0, stream>>>(
      f1, w2b, nullptr, part, DM/256, DF/4, DF, DF, DM, 1.f, (long)NTOK*DM);
  comb_k<<<(NTOK*DM)/1024, 256, 0, stream>>>(part, b2, out1, out);
}